// Round 21
// baseline (122.954 us; speedup 1.0000x reference)
//
#include <hip/hip_runtime.h>
#include <hip/hip_bf16.h>

#define BB 2
#define NN 2048
#define CC 768
#define HH 12
#define DD 64
#define MM 4096
#define N3 2304

typedef __attribute__((ext_vector_type(8))) short bf16x8;
typedef __attribute__((ext_vector_type(4))) float f32x4;

// 0.125 (1/sqrt(D)) * log2(e) folded into Q so softmax runs in base-2 units
#define QSCALE 0.18033688011112043f

// K-dim fragment-contiguous permutation (applied to x, W_qkv, W_out, q, k, v, y):
// within each 32-element k-block, element at offset o is stored at
// p(o) = ((o&15)>>2)*8 + ((o>>4)&1)*4 + (o&3).

__device__ __forceinline__ unsigned short f2bf(float f) {
    union { float f; unsigned u; } v; v.f = f;
    unsigned r = v.u + 0x7FFFu + ((v.u >> 16) & 1u);
    return (unsigned short)(r >> 16);
}

__device__ __forceinline__ short f2bf_rn(float f) {
    union { __hip_bfloat16 h; short s; } v;
    v.h = __float2bfloat16(f);
    return v.s;
}

__device__ __forceinline__ float exp2_hw(float x) {
    float r;
    asm("v_exp_f32 %0, %1" : "=v"(r) : "v"(x));
    return r;
}

__device__ __forceinline__ bf16x8 ld_frag16(const unsigned short* p) {
    bf16x8 r;
    __builtin_memcpy(&r, p, 16);
    return r;
}

__device__ __forceinline__ void gload16(const unsigned short* g, unsigned short* l) {
    __builtin_amdgcn_global_load_lds(
        (const __attribute__((address_space(1))) void*)g,
        (__attribute__((address_space(3))) void*)l,
        16, 0, 0);
}

// convert + K-permute: x f32 row-major (width % 32 == 0) -> bf16 permuted
__global__ void k_cvt(const float* __restrict__ s, unsigned short* __restrict__ d, int n4) {
    int i = blockIdx.x * blockDim.x + threadIdx.x;
    int st = gridDim.x * blockDim.x;
    for (; i < n4; i += st) {
        float4 v = ((const float4*)s)[i];
        ushort4 o;
        o.x = f2bf(v.x); o.y = f2bf(v.y); o.z = f2bf(v.z); o.w = f2bf(v.w);
        int f = i * 4;
        int dst = (f & ~31) + ((i & 3) << 3) + (((i >> 2) & 1) << 2);
        *(ushort4*)(d + dst) = o;
    }
}

// transpose+convert+K-permute: src f32 [R][Cc] -> dst bf16 [Cc][R-permuted]
__global__ void k_cvtT(const float* __restrict__ s, unsigned short* __restrict__ d,
                       int R, int Cc) {
    __shared__ unsigned short t[64][72];
    const int c0 = blockIdx.x * 64, r0 = blockIdx.y * 64;
    const int tr = threadIdx.x >> 4;
    const int tc = (threadIdx.x & 15) * 4;
#pragma unroll
    for (int i = 0; i < 4; i++) {
        int r = tr + i * 16;
        float4 v = *(const float4*)(s + (size_t)(r0 + r) * Cc + c0 + tc);
        t[tc + 0][r] = f2bf(v.x);
        t[tc + 1][r] = f2bf(v.y);
        t[tc + 2][r] = f2bf(v.z);
        t[tc + 3][r] = f2bf(v.w);
    }
    __syncthreads();
    const int wr = threadIdx.x >> 2;
    const int wc = (threadIdx.x & 3) * 16;
    unsigned short* drow = d + (size_t)(c0 + wr) * R + r0;
#pragma unroll
    for (int g = 0; g < 4; g++) {
        int k4 = wc + g * 4;
        int o = k4 & 31;
        int p = (((o & 15) >> 2) << 3) + (((o >> 4) & 1) << 2);
        ushort4 v4 = *(ushort4*)&t[wr][k4];
        *(ushort4*)(drow + (k4 & ~31) + p) = v4;
    }
}

// ---------------- GEMM1: qkv = x @ W_qkv + b, fused RoPE ----------------
// grid (32, 18), block 256 (4 waves). Tile 128(M) x 128(N) — 576 blocks fit in one
// scheduling round (<= 768 resident) — each wave owns 32(M) x 128(N), acc[2][8].
// 128-col tile = exactly 2 heads; RoPE fn^2 partner stays within each head.
__launch_bounds__(256)
__global__ void k_qkv(const unsigned short* __restrict__ xb,
                      const unsigned short* __restrict__ wt,
                      const float* __restrict__ bias,
                      const float* __restrict__ sinp,
                      const float* __restrict__ cosp,
                      unsigned short* __restrict__ qws,
                      unsigned short* __restrict__ kws,
                      unsigned short* __restrict__ vws) {
    __shared__ unsigned short As[2][128 * 32];
    __shared__ unsigned short Bs[2][128 * 32];
    const int tid = threadIdx.x;
    const int lane = tid & 63, w = tid >> 6;
    const int ql = lane & 15, lg = lane >> 4;
    const int row0 = blockIdx.x * 128;
    const int j0 = blockIdx.y * 128;

    f32x4 acc[2][8];
#pragma unroll
    for (int a = 0; a < 2; a++)
#pragma unroll
        for (int b = 0; b < 8; b++) acc[a][b] = f32x4{0.f, 0.f, 0.f, 0.f};

    const int sr = lane >> 2;
    const int sc = (lane & 3) * 8;

    auto stage = [&](int bi, int k0) {
#pragma unroll
        for (int c = 0; c < 2; c++) {
            int j = w * 2 + c;
            gload16(xb + (size_t)(row0 + j * 16 + sr) * CC + k0 + sc, &As[bi][j * 512]);
            gload16(wt + (size_t)(j0 + j * 16 + sr) * CC + k0 + sc, &Bs[bi][j * 512]);
        }
    };

    stage(0, 0);
    __syncthreads();

    int bufi = 0;
    for (int k0 = 0; k0 < CC; k0 += 32) {
        if (k0 + 32 < CC) stage(bufi ^ 1, k0 + 32);
        bf16x8 af[2], bfr[8];
#pragma unroll
        for (int fr = 0; fr < 2; fr++)
            af[fr] = ld_frag16(&As[bufi][(w * 32 + fr * 16 + ql) * 32 + lg * 8]);
#pragma unroll
        for (int fn = 0; fn < 8; fn++)
            bfr[fn] = ld_frag16(&Bs[bufi][(fn * 16 + ql) * 32 + lg * 8]);
#pragma unroll
        for (int fr = 0; fr < 2; fr++)
#pragma unroll
            for (int fn = 0; fn < 8; fn++)
                acc[fr][fn] = __builtin_amdgcn_mfma_f32_16x16x32_bf16(af[fr], bfr[fn], acc[fr][fn], 0, 0, 0);
        __syncthreads();
        bufi ^= 1;
    }

    float vals[2][8][4];
#pragma unroll
    for (int fr = 0; fr < 2; fr++)
#pragma unroll
        for (int fn = 0; fn < 8; fn++) {
            float bj = bias[j0 + fn * 16 + ql];
#pragma unroll
            for (int r = 0; r < 4; r++) vals[fr][fn][r] = acc[fr][fn][r] + bj;
        }
    const int t = j0 / CC;             // 128-col tile entirely one of q/k/v
    const int h0 = (j0 % CC) >> 6;     // first of the two heads in this tile
    if (t < 2) {
        unsigned short* outp = (t == 0) ? qws : kws;
        const float qs = (t == 0) ? QSCALE : 1.0f;
#pragma unroll
        for (int fr = 0; fr < 2; fr++)
#pragma unroll
            for (int r = 0; r < 4; r++) {
                int m = row0 + w * 32 + fr * 16 + lg * 4 + r;
                int b = m >> 11, n = m & (NN - 1);
#pragma unroll
                for (int fn = 0; fn < 8; fn++) {
                    int d = (fn & 3) * 16 + ql;
                    int h = h0 + (fn >> 2);
                    float cv = cosp[n * DD + d], sv = sinp[n * DD + d];
                    float other = vals[fr][fn ^ 2][r];  // partner at d +/- 32 (same head)
                    float rv = (vals[fr][fn][r] * cv + (((fn & 3) < 2) ? -other : other) * sv) * qs;
                    int dcol = ((fn & 3) >> 1) * 32 + (ql >> 2) * 8 + (fn & 1) * 4 + (ql & 3);
                    outp[((size_t)(b * HH + h) * NN + n) * DD + dcol] = f2bf(rv);
                }
            }
    } else {
#pragma unroll
        for (int fr = 0; fr < 2; fr++)
#pragma unroll
            for (int r = 0; r < 4; r++) {
                int m = row0 + w * 32 + fr * 16 + lg * 4 + r;
                int b = m >> 11, n = m & (NN - 1);
                int ncol = (n & ~31) + lg * 8 + (fr & 1) * 4 + r;
#pragma unroll
                for (int fn = 0; fn < 8; fn++) {
                    int d = (fn & 3) * 16 + ql;
                    int h = h0 + (fn >> 2);
                    vws[((size_t)(b * HH + h) * DD + d) * NN + ncol] = f2bf(vals[fr][fn][r]);
                }
            }
    }
}

// ---------------- Attention, 4-wave blocks + split-K2 (R20, unchanged) ----------------
__launch_bounds__(256)
__global__ void k_attn4(const unsigned short* __restrict__ qws,
                        const unsigned short* __restrict__ kws,
                        const unsigned short* __restrict__ vws,
                        float* __restrict__ pA,
                        float* __restrict__ pm,
                        float* __restrict__ pl) {
    __shared__ unsigned short Ks[2][64][72];  // [buf][kk][d-permuted]
    __shared__ unsigned short Vs[2][64][72];  // [buf][d][kk-permuted]
    const int tid = threadIdx.x;
    const int lane = tid & 63, w = tid >> 6;
    const int ql = lane & 15, lg = lane >> 4;
    const int d0 = blockIdx.x;
    const int bh = (d0 & 7) + 8 * (d0 >> 8);   // 3 heads per XCD class
    const int kh = (d0 >> 3) & 1;              // key half
    const int qb = (d0 >> 4) & 15;             // q block (128 q)
    const int qw = qb * 128 + w * 32;
    const unsigned short* Qp = qws + (size_t)bh * NN * DD;
    const unsigned short* Kp = kws + (size_t)bh * NN * DD;
    const unsigned short* Vp = vws + (size_t)bh * DD * NN;

    bf16x8 qf[2][2];
#pragma unroll
    for (int fn = 0; fn < 2; fn++)
#pragma unroll
        for (int kb = 0; kb < 2; kb++)
            qf[fn][kb] = ld_frag16(Qp + (size_t)(qw + fn * 16 + ql) * DD + kb * 32 + lg * 8);

    f32x4 oacc[4][2];
#pragma unroll
    for (int a = 0; a < 4; a++)
#pragma unroll
        for (int b = 0; b < 2; b++) oacc[a][b] = f32x4{0.f, 0.f, 0.f, 0.f};
    float mrun[2] = {-1e30f, -1e30f}, lrun[2] = {0.f, 0.f};

    const int srow = tid >> 2;          // 0..63
    const int su = (tid & 3) * 16;      // short offset within row
    const int kt0 = kh * 16;

    // prologue: stage tile kt0 (2 uint4 K + 2 uint4 V per thread)
#pragma unroll
    for (int j = 0; j < 2; j++) {
        *(uint4*)&Ks[0][srow][su + j * 8] = *(const uint4*)(Kp + (size_t)(kt0 * 64 + srow) * DD + su + j * 8);
        *(uint4*)&Vs[0][srow][su + j * 8] = *(const uint4*)(Vp + (size_t)srow * NN + kt0 * 64 + su + j * 8);
    }
    __syncthreads();

    int cur = 0;
    for (int t = 0; t < 16; t++) {
        const int kt = kt0 + t;
        uint4 kn[2], vn[2];
        const bool hasn = (t + 1 < 16);
        if (hasn) {
#pragma unroll
            for (int j = 0; j < 2; j++) {
                kn[j] = *(const uint4*)(Kp + (size_t)((kt + 1) * 64 + srow) * DD + su + j * 8);
                vn[j] = *(const uint4*)(Vp + (size_t)srow * NN + (kt + 1) * 64 + su + j * 8);
            }
        }
        const unsigned short (*Kc)[72] = Ks[cur];
        const unsigned short (*Vc)[72] = Vs[cur];

        f32x4 sacc[4][2];
#pragma unroll
        for (int a = 0; a < 4; a++)
#pragma unroll
            for (int b = 0; b < 2; b++) sacc[a][b] = f32x4{0.f, 0.f, 0.f, 0.f};
        __builtin_amdgcn_s_setprio(1);
#pragma unroll
        for (int kb = 0; kb < 2; kb++) {
            bf16x8 kf[4];
#pragma unroll
            for (int fr = 0; fr < 4; fr++)
                kf[fr] = ld_frag16(&Kc[fr * 16 + ql][kb * 32 + lg * 8]);
#pragma unroll
            for (int fr = 0; fr < 4; fr++)
#pragma unroll
                for (int fn = 0; fn < 2; fn++)
                    sacc[fr][fn] = __builtin_amdgcn_mfma_f32_16x16x32_bf16(kf[fr], qf[fn][kb], sacc[fr][fn], 0, 0, 0);
        }
        __builtin_amdgcn_s_setprio(0);

        bf16x8 pB[2][2];
#pragma unroll
        for (int fn = 0; fn < 2; fn++) {
            float ma = fmaxf(fmaxf(sacc[0][fn][0], sacc[0][fn][1]), fmaxf(sacc[0][fn][2], sacc[0][fn][3]));
            float mb = fmaxf(fmaxf(sacc[1][fn][0], sacc[1][fn][1]), fmaxf(sacc[1][fn][2], sacc[1][fn][3]));
            float mc = fmaxf(fmaxf(sacc[2][fn][0], sacc[2][fn][1]), fmaxf(sacc[2][fn][2], sacc[2][fn][3]));
            float md = fmaxf(fmaxf(sacc[3][fn][0], sacc[3][fn][1]), fmaxf(sacc[3][fn][2], sacc[3][fn][3]));
            float tm = fmaxf(fmaxf(ma, mb), fmaxf(mc, md));
            tm = fmaxf(tm, __shfl_xor(tm, 16));
            tm = fmaxf(tm, __shfl_xor(tm, 32));
            if (__any(tm > mrun[fn] + 8.0f)) {
                float mn = fmaxf(mrun[fn], tm);
                float scl = exp2_hw(mrun[fn] - mn);
                lrun[fn] *= scl;
#pragma unroll
                for (int db = 0; db < 4; db++) oacc[db][fn] *= scl;
                mrun[fn] = mn;
            }
            float ts = 0.f;
#pragma unroll
            for (int fr = 0; fr < 4; fr++)
#pragma unroll
                for (int r = 0; r < 4; r++) {
                    float p = exp2_hw(sacc[fr][fn][r] - mrun[fn]);
                    sacc[fr][fn][r] = p;
                    ts += p;
                }
            ts += __shfl_xor(ts, 16);
            ts += __shfl_xor(ts, 32);
            lrun[fn] += ts;

#pragma unroll
            for (int kkb = 0; kkb < 2; kkb++) {
                bf16x8 t8;
#pragma unroll
                for (int e = 0; e < 8; e++)
                    t8[e] = f2bf_rn(sacc[kkb * 2 + (e >> 2)][fn][e & 3]);
                pB[fn][kkb] = t8;
            }
        }

        __builtin_amdgcn_s_setprio(1);
#pragma unroll
        for (int db = 0; db < 4; db++) {
            bf16x8 va[2];
#pragma unroll
            for (int kkb = 0; kkb < 2; kkb++)
                va[kkb] = ld_frag16(&Vc[db * 16 + ql][kkb * 32 + lg * 8]);
#pragma unroll
            for (int kkb = 0; kkb < 2; kkb++)
#pragma unroll
                for (int fn = 0; fn < 2; fn++)
                    oacc[db][fn] = __builtin_amdgcn_mfma_f32_16x16x32_bf16(va[kkb], pB[fn][kkb], oacc[db][fn], 0, 0, 0);
        }
        __builtin_amdgcn_s_setprio(0);

        if (hasn) {
#pragma unroll
            for (int j = 0; j < 2; j++) {
                *(uint4*)&Ks[cur ^ 1][srow][su + j * 8] = kn[j];
                *(uint4*)&Vs[cur ^ 1][srow][su + j * 8] = vn[j];
            }
            __syncthreads();
            cur ^= 1;
        }
    }

    // write unnormalized partials: A[kh][bh][q][d] f32, stats per q
#pragma unroll
    for (int fn = 0; fn < 2; fn++) {
        int q = qw + fn * 16 + ql;
        float* ap = pA + (((size_t)kh * 24 + bh) * NN + q) * DD + lg * 4;
#pragma unroll
        for (int db = 0; db < 4; db++)
            *(f32x4*)(ap + db * 16) = oacc[db][fn];
        if (lg == 0) {
            pm[((size_t)kh * 24 + bh) * NN + q] = mrun[fn];
            pl[((size_t)kh * 24 + bh) * NN + q] = lrun[fn];
        }
    }
}

// split-K combine: y = (A0*e0 + A1*e1) / (l0*e0 + l1*e1), written K-permuted bf16
__global__ void k_comb(const float* __restrict__ pA,
                       const float* __restrict__ pm,
                       const float* __restrict__ pl,
                       unsigned short* __restrict__ yws) {
    const int idx = blockIdx.x * blockDim.x + threadIdx.x;
    const int qg = idx >> 4;
    const int d4 = (idx & 15) * 4;
    const int bh = qg >> 11, q = qg & (NN - 1);
    const int b = bh / HH, h = bh % HH;
    const size_t half = (size_t)24 * NN * DD;
    float m0 = pm[qg], m1 = pm[24 * NN + qg];
    float l0 = pl[qg], l1 = pl[24 * NN + qg];
    float M = fmaxf(m0, m1);
    float e0 = exp2_hw(m0 - M), e1 = exp2_hw(m1 - M);
    float inv = 1.0f / (l0 * e0 + l1 * e1);
    f32x4 a0 = *(const f32x4*)(pA + (size_t)qg * DD + d4);
    f32x4 a1 = *(const f32x4*)(pA + half + (size_t)qg * DD + d4);
    ushort4 o;
    o.x = f2bf((a0[0] * e0 + a1[0] * e1) * inv);
    o.y = f2bf((a0[1] * e0 + a1[1] * e1) * inv);
    o.z = f2bf((a0[2] * e0 + a1[2] * e1) * inv);
    o.w = f2bf((a0[3] * e0 + a1[3] * e1) * inv);
    int dcol = (d4 & ~31) + ((d4 >> 2) & 3) * 8 + ((d4 >> 4) & 1) * 4;
    *(ushort4*)(yws + (size_t)(b * NN + q) * CC + h * DD + dcol) = o;
}

// ---------------- GEMM2: out = y @ W_out + b_out (f32 out) ----------------
__launch_bounds__(256)
__global__ void k_out(const unsigned short* __restrict__ yb,
                      const unsigned short* __restrict__ wt,
                      const float* __restrict__ bias,
                      float* __restrict__ out) {
    __shared__ unsigned short As[2][128 * 32];
    __shared__ unsigned short Bs[2][64 * 32];
    const int tid = threadIdx.x;
    const int lane = tid & 63, w = tid >> 6;
    const int ql = lane & 15, lg = lane >> 4;
    const int row0 = blockIdx.x * 128;
    const int j0 = blockIdx.y * 64;

    f32x4 acc[2][4];
#pragma unroll
    for (int a = 0; a < 2; a++)
#pragma unroll
        for (int b = 0; b < 4; b++) acc[a][b] = f32x4{0.f, 0.f, 0.f, 0.f};

    const int sr = lane >> 2;
    const int sc = (lane & 3) * 8;

    auto stage = [&](int bi, int k0) {
#pragma unroll
        for (int c = 0; c < 2; c++) {
            int j = w * 2 + c;
            gload16(yb + (size_t)(row0 + j * 16 + sr) * CC + k0 + sc, &As[bi][j * 512]);
        }
        gload16(wt + (size_t)(j0 + w * 16 + sr) * CC + k0 + sc, &Bs[bi][w * 512]);
    };

    stage(0, 0);
    __syncthreads();

    int bufi = 0;
    for (int k0 = 0; k0 < CC; k0 += 32) {
        if (k0 + 32 < CC) stage(bufi ^ 1, k0 + 32);
        bf16x8 af[2], bfr[4];
#pragma unroll
        for (int fr = 0; fr < 2; fr++)
            af[fr] = ld_frag16(&As[bufi][(w * 32 + fr * 16 + ql) * 32 + lg * 8]);
#pragma unroll
        for (int fn = 0; fn < 4; fn++)
            bfr[fn] = ld_frag16(&Bs[bufi][(fn * 16 + ql) * 32 + lg * 8]);
#pragma unroll
        for (int fr = 0; fr < 2; fr++)
#pragma unroll
            for (int fn = 0; fn < 4; fn++)
                acc[fr][fn] = __builtin_amdgcn_mfma_f32_16x16x32_bf16(af[fr], bfr[fn], acc[fr][fn], 0, 0, 0);
        __syncthreads();
        bufi ^= 1;
    }

#pragma unroll
    for (int fr = 0; fr < 2; fr++)
#pragma unroll
        for (int fn = 0; fn < 4; fn++) {
            float bj = bias[j0 + fn * 16 + ql];
#pragma unroll
            for (int r = 0; r < 4; r++) {
                int m = row0 + w * 32 + fr * 16 + lg * 4 + r;
                out[(size_t)m * CC + j0 + fn * 16 + ql] = acc[fr][fn][r] + bj;
            }
        }
}

extern "C" void kernel_launch(void* const* d_in, const int* in_sizes, int n_in,
                              void* d_out, int out_size, void* d_ws, size_t ws_size,
                              hipStream_t stream) {
    const float* x    = (const float*)d_in[0];
    const float* sinp = (const float*)d_in[1];
    const float* cosp = (const float*)d_in[2];
    const float* wqkv = (const float*)d_in[3];
    const float* bqkv = (const float*)d_in[4];
    const float* wout = (const float*)d_in[5];
    const float* bout = (const float*)d_in[6];
    float* out = (float*)d_out;
    char* ws = (char*)d_ws;

    unsigned short* xb  = (unsigned short*)(ws);            // 4096x768 bf16 (K-perm)
    unsigned short* wqb = (unsigned short*)(ws + 6291456);  // Wt_qkv [2304][768-perm]
    unsigned short* wob = (unsigned short*)(ws + 9830400);  // Wt_out [768][768-perm]
    unsigned short* qws = (unsigned short*)(ws + 11010048);
    unsigned short* kws = (unsigned short*)(ws + 17301504);
    unsigned short* vws = (unsigned short*)(ws + 23592960);
    unsigned short* yws = (unsigned short*)(ws + 29884416); // y [4096][768-perm]
    float* pA = (float*)(ws + 36175872);                    // 2 x 24 x 2048 x 64 f32
    float* pm = (float*)(ws + 61341696);                    // 2 x 24 x 2048 f32
    float* pl = (float*)(ws + 61734912);                    // 2 x 24 x 2048 f32
    if (ws_size < 62128128) return;  // split-K workspace verified present (R18)

    k_cvt<<<dim3(512), dim3(256), 0, stream>>>(x, xb, MM * CC / 4);
    k_cvtT<<<dim3(36, 12), dim3(256), 0, stream>>>(wqkv, wqb, CC, N3);
    k_cvtT<<<dim3(12, 12), dim3(256), 0, stream>>>(wout, wob, CC, CC);
    k_qkv<<<dim3(32, 18), dim3(256), 0, stream>>>(xb, wqb, bqkv, sinp, cosp, qws, kws, vws);
    k_attn4<<<dim3(768), dim3(256), 0, stream>>>(qws, kws, vws, pA, pm, pl);
    k_comb<<<dim3(3072), dim3(256), 0, stream>>>(pA, pm, pl, yws);
    k_out<<<dim3(32, 12), dim3(256), 0, stream>>>(yws, wob, bout, out);
}

// Round 22
// 117.278 us; speedup vs baseline: 1.0484x; 1.0484x over previous
//
#include <hip/hip_runtime.h>
#include <hip/hip_bf16.h>

#define BB 2
#define NN 2048
#define CC 768
#define HH 12
#define DD 64
#define MM 4096
#define N3 2304

typedef __attribute__((ext_vector_type(8))) short bf16x8;
typedef __attribute__((ext_vector_type(4))) float f32x4;

// 0.125 (1/sqrt(D)) * log2(e) folded into Q so softmax runs in base-2 units
#define QSCALE 0.18033688011112043f

// K-dim fragment-contiguous permutation (applied to x, W_qkv, W_out, q, k, v, y):
// within each 32-element k-block, element at offset o is stored at
// p(o) = ((o&15)>>2)*8 + ((o>>4)&1)*4 + (o&3).

__device__ __forceinline__ unsigned short f2bf(float f) {
    union { float f; unsigned u; } v; v.f = f;
    unsigned r = v.u + 0x7FFFu + ((v.u >> 16) & 1u);
    return (unsigned short)(r >> 16);
}

__device__ __forceinline__ short f2bf_rn(float f) {
    union { __hip_bfloat16 h; short s; } v;
    v.h = __float2bfloat16(f);
    return v.s;
}

__device__ __forceinline__ float exp2_hw(float x) {
    float r;
    asm("v_exp_f32 %0, %1" : "=v"(r) : "v"(x));
    return r;
}

__device__ __forceinline__ bf16x8 ld_frag16(const unsigned short* p) {
    bf16x8 r;
    __builtin_memcpy(&r, p, 16);
    return r;
}

__device__ __forceinline__ void gload16(const unsigned short* g, unsigned short* l) {
    __builtin_amdgcn_global_load_lds(
        (const __attribute__((address_space(1))) void*)g,
        (__attribute__((address_space(3))) void*)l,
        16, 0, 0);
}

// convert + K-permute: x f32 row-major (width % 32 == 0) -> bf16 permuted
__global__ void k_cvt(const float* __restrict__ s, unsigned short* __restrict__ d, int n4) {
    int i = blockIdx.x * blockDim.x + threadIdx.x;
    int st = gridDim.x * blockDim.x;
    for (; i < n4; i += st) {
        float4 v = ((const float4*)s)[i];
        ushort4 o;
        o.x = f2bf(v.x); o.y = f2bf(v.y); o.z = f2bf(v.z); o.w = f2bf(v.w);
        int f = i * 4;
        int dst = (f & ~31) + ((i & 3) << 3) + (((i >> 2) & 1) << 2);
        *(ushort4*)(d + dst) = o;
    }
}

// transpose+convert+K-permute: src f32 [R][Cc] -> dst bf16 [Cc][R-permuted]
__global__ void k_cvtT(const float* __restrict__ s, unsigned short* __restrict__ d,
                       int R, int Cc) {
    __shared__ unsigned short t[64][72];
    const int c0 = blockIdx.x * 64, r0 = blockIdx.y * 64;
    const int tr = threadIdx.x >> 4;
    const int tc = (threadIdx.x & 15) * 4;
#pragma unroll
    for (int i = 0; i < 4; i++) {
        int r = tr + i * 16;
        float4 v = *(const float4*)(s + (size_t)(r0 + r) * Cc + c0 + tc);
        t[tc + 0][r] = f2bf(v.x);
        t[tc + 1][r] = f2bf(v.y);
        t[tc + 2][r] = f2bf(v.z);
        t[tc + 3][r] = f2bf(v.w);
    }
    __syncthreads();
    const int wr = threadIdx.x >> 2;
    const int wc = (threadIdx.x & 3) * 16;
    unsigned short* drow = d + (size_t)(c0 + wr) * R + r0;
#pragma unroll
    for (int g = 0; g < 4; g++) {
        int k4 = wc + g * 4;
        int o = k4 & 31;
        int p = (((o & 15) >> 2) << 3) + (((o >> 4) & 1) << 2);
        ushort4 v4 = *(ushort4*)&t[wr][k4];
        *(ushort4*)(drow + (k4 & ~31) + p) = v4;
    }
}

// ---------------- GEMM1: qkv = x @ W_qkv + b, fused RoPE ----------------
// grid (32, 36), block 256. Tile 128(M) x 64(N) — replicated-best for this shape
// (128x128 regressed in R3/R10/R21). gload_lds staging, dbuf, 1 barrier/k-step.
__launch_bounds__(256)
__global__ void k_qkv(const unsigned short* __restrict__ xb,
                      const unsigned short* __restrict__ wt,
                      const float* __restrict__ bias,
                      const float* __restrict__ sinp,
                      const float* __restrict__ cosp,
                      unsigned short* __restrict__ qws,
                      unsigned short* __restrict__ kws,
                      unsigned short* __restrict__ vws) {
    __shared__ unsigned short As[2][128 * 32];
    __shared__ unsigned short Bs[2][64 * 32];
    const int tid = threadIdx.x;
    const int lane = tid & 63, w = tid >> 6;
    const int ql = lane & 15, lg = lane >> 4;
    const int row0 = blockIdx.x * 128;
    const int j0 = blockIdx.y * 64;

    f32x4 acc[2][4];
#pragma unroll
    for (int a = 0; a < 2; a++)
#pragma unroll
        for (int b = 0; b < 4; b++) acc[a][b] = f32x4{0.f, 0.f, 0.f, 0.f};

    const int sr = lane >> 2;
    const int sc = (lane & 3) * 8;

    auto stage = [&](int bi, int k0) {
#pragma unroll
        for (int c = 0; c < 2; c++) {
            int j = w * 2 + c;
            gload16(xb + (size_t)(row0 + j * 16 + sr) * CC + k0 + sc, &As[bi][j * 512]);
        }
        gload16(wt + (size_t)(j0 + w * 16 + sr) * CC + k0 + sc, &Bs[bi][w * 512]);
    };

    stage(0, 0);
    __syncthreads();

    int bufi = 0;
    for (int k0 = 0; k0 < CC; k0 += 32) {
        if (k0 + 32 < CC) stage(bufi ^ 1, k0 + 32);
        bf16x8 af[2], bfr[4];
#pragma unroll
        for (int fr = 0; fr < 2; fr++)
            af[fr] = ld_frag16(&As[bufi][(w * 32 + fr * 16 + ql) * 32 + lg * 8]);
#pragma unroll
        for (int fn = 0; fn < 4; fn++)
            bfr[fn] = ld_frag16(&Bs[bufi][(fn * 16 + ql) * 32 + lg * 8]);
#pragma unroll
        for (int fr = 0; fr < 2; fr++)
#pragma unroll
            for (int fn = 0; fn < 4; fn++)
                acc[fr][fn] = __builtin_amdgcn_mfma_f32_16x16x32_bf16(af[fr], bfr[fn], acc[fr][fn], 0, 0, 0);
        __syncthreads();
        bufi ^= 1;
    }

    float vals[2][4][4];
#pragma unroll
    for (int fr = 0; fr < 2; fr++)
#pragma unroll
        for (int fn = 0; fn < 4; fn++) {
            float bj = bias[j0 + fn * 16 + ql];
#pragma unroll
            for (int r = 0; r < 4; r++) vals[fr][fn][r] = acc[fr][fn][r] + bj;
        }
    const int t = j0 / CC;
    const int h = (j0 % CC) >> 6;
    if (t < 2) {
        unsigned short* outp = (t == 0) ? qws : kws;
        const float qs = (t == 0) ? QSCALE : 1.0f;
#pragma unroll
        for (int fr = 0; fr < 2; fr++)
#pragma unroll
            for (int r = 0; r < 4; r++) {
                int m = row0 + w * 32 + fr * 16 + lg * 4 + r;
                int b = m >> 11, n = m & (NN - 1);
#pragma unroll
                for (int fn = 0; fn < 4; fn++) {
                    int d = fn * 16 + ql;
                    float cv = cosp[n * DD + d], sv = sinp[n * DD + d];
                    float other = vals[fr][fn ^ 2][r];
                    float rv = (vals[fr][fn][r] * cv + ((fn < 2) ? -other : other) * sv) * qs;
                    int dcol = (fn >> 1) * 32 + (ql >> 2) * 8 + (fn & 1) * 4 + (ql & 3);
                    outp[((size_t)(b * HH + h) * NN + n) * DD + dcol] = f2bf(rv);
                }
            }
    } else {
#pragma unroll
        for (int fr = 0; fr < 2; fr++)
#pragma unroll
            for (int r = 0; r < 4; r++) {
                int m = row0 + w * 32 + fr * 16 + lg * 4 + r;
                int b = m >> 11, n = m & (NN - 1);
                int ncol = (n & ~31) + lg * 8 + (fr & 1) * 4 + r;
#pragma unroll
                for (int fn = 0; fn < 4; fn++) {
                    int d = fn * 16 + ql;
                    vws[((size_t)(b * HH + h) * DD + d) * NN + ncol] = f2bf(vals[fr][fn][r]);
                }
            }
    }
}

// ---------------- Attention, 4-wave blocks + split-K2 (R20, measured best) ----------------
__launch_bounds__(256)
__global__ void k_attn4(const unsigned short* __restrict__ qws,
                        const unsigned short* __restrict__ kws,
                        const unsigned short* __restrict__ vws,
                        float* __restrict__ pA,
                        float* __restrict__ pm,
                        float* __restrict__ pl) {
    __shared__ unsigned short Ks[2][64][72];  // [buf][kk][d-permuted]
    __shared__ unsigned short Vs[2][64][72];  // [buf][d][kk-permuted]
    const int tid = threadIdx.x;
    const int lane = tid & 63, w = tid >> 6;
    const int ql = lane & 15, lg = lane >> 4;
    const int d0 = blockIdx.x;
    const int bh = (d0 & 7) + 8 * (d0 >> 8);   // 3 heads per XCD class
    const int kh = (d0 >> 3) & 1;              // key half
    const int qb = (d0 >> 4) & 15;             // q block (128 q)
    const int qw = qb * 128 + w * 32;
    const unsigned short* Qp = qws + (size_t)bh * NN * DD;
    const unsigned short* Kp = kws + (size_t)bh * NN * DD;
    const unsigned short* Vp = vws + (size_t)bh * DD * NN;

    bf16x8 qf[2][2];
#pragma unroll
    for (int fn = 0; fn < 2; fn++)
#pragma unroll
        for (int kb = 0; kb < 2; kb++)
            qf[fn][kb] = ld_frag16(Qp + (size_t)(qw + fn * 16 + ql) * DD + kb * 32 + lg * 8);

    f32x4 oacc[4][2];
#pragma unroll
    for (int a = 0; a < 4; a++)
#pragma unroll
        for (int b = 0; b < 2; b++) oacc[a][b] = f32x4{0.f, 0.f, 0.f, 0.f};
    float mrun[2] = {-1e30f, -1e30f}, lrun[2] = {0.f, 0.f};

    const int srow = tid >> 2;          // 0..63
    const int su = (tid & 3) * 16;      // short offset within row
    const int kt0 = kh * 16;

    // prologue: stage tile kt0 (2 uint4 K + 2 uint4 V per thread)
#pragma unroll
    for (int j = 0; j < 2; j++) {
        *(uint4*)&Ks[0][srow][su + j * 8] = *(const uint4*)(Kp + (size_t)(kt0 * 64 + srow) * DD + su + j * 8);
        *(uint4*)&Vs[0][srow][su + j * 8] = *(const uint4*)(Vp + (size_t)srow * NN + kt0 * 64 + su + j * 8);
    }
    __syncthreads();

    int cur = 0;
    for (int t = 0; t < 16; t++) {
        const int kt = kt0 + t;
        uint4 kn[2], vn[2];
        const bool hasn = (t + 1 < 16);
        if (hasn) {
#pragma unroll
            for (int j = 0; j < 2; j++) {
                kn[j] = *(const uint4*)(Kp + (size_t)((kt + 1) * 64 + srow) * DD + su + j * 8);
                vn[j] = *(const uint4*)(Vp + (size_t)srow * NN + (kt + 1) * 64 + su + j * 8);
            }
        }
        const unsigned short (*Kc)[72] = Ks[cur];
        const unsigned short (*Vc)[72] = Vs[cur];

        f32x4 sacc[4][2];
#pragma unroll
        for (int a = 0; a < 4; a++)
#pragma unroll
            for (int b = 0; b < 2; b++) sacc[a][b] = f32x4{0.f, 0.f, 0.f, 0.f};
        __builtin_amdgcn_s_setprio(1);
#pragma unroll
        for (int kb = 0; kb < 2; kb++) {
            bf16x8 kf[4];
#pragma unroll
            for (int fr = 0; fr < 4; fr++)
                kf[fr] = ld_frag16(&Kc[fr * 16 + ql][kb * 32 + lg * 8]);
#pragma unroll
            for (int fr = 0; fr < 4; fr++)
#pragma unroll
                for (int fn = 0; fn < 2; fn++)
                    sacc[fr][fn] = __builtin_amdgcn_mfma_f32_16x16x32_bf16(kf[fr], qf[fn][kb], sacc[fr][fn], 0, 0, 0);
        }
        __builtin_amdgcn_s_setprio(0);

        bf16x8 pB[2][2];
#pragma unroll
        for (int fn = 0; fn < 2; fn++) {
            float ma = fmaxf(fmaxf(sacc[0][fn][0], sacc[0][fn][1]), fmaxf(sacc[0][fn][2], sacc[0][fn][3]));
            float mb = fmaxf(fmaxf(sacc[1][fn][0], sacc[1][fn][1]), fmaxf(sacc[1][fn][2], sacc[1][fn][3]));
            float mc = fmaxf(fmaxf(sacc[2][fn][0], sacc[2][fn][1]), fmaxf(sacc[2][fn][2], sacc[2][fn][3]));
            float md = fmaxf(fmaxf(sacc[3][fn][0], sacc[3][fn][1]), fmaxf(sacc[3][fn][2], sacc[3][fn][3]));
            float tm = fmaxf(fmaxf(ma, mb), fmaxf(mc, md));
            tm = fmaxf(tm, __shfl_xor(tm, 16));
            tm = fmaxf(tm, __shfl_xor(tm, 32));
            if (__any(tm > mrun[fn] + 8.0f)) {
                float mn = fmaxf(mrun[fn], tm);
                float scl = exp2_hw(mrun[fn] - mn);
                lrun[fn] *= scl;
#pragma unroll
                for (int db = 0; db < 4; db++) oacc[db][fn] *= scl;
                mrun[fn] = mn;
            }
            float ts = 0.f;
#pragma unroll
            for (int fr = 0; fr < 4; fr++)
#pragma unroll
                for (int r = 0; r < 4; r++) {
                    float p = exp2_hw(sacc[fr][fn][r] - mrun[fn]);
                    sacc[fr][fn][r] = p;
                    ts += p;
                }
            ts += __shfl_xor(ts, 16);
            ts += __shfl_xor(ts, 32);
            lrun[fn] += ts;

#pragma unroll
            for (int kkb = 0; kkb < 2; kkb++) {
                bf16x8 t8;
#pragma unroll
                for (int e = 0; e < 8; e++)
                    t8[e] = f2bf_rn(sacc[kkb * 2 + (e >> 2)][fn][e & 3]);
                pB[fn][kkb] = t8;
            }
        }

        __builtin_amdgcn_s_setprio(1);
#pragma unroll
        for (int db = 0; db < 4; db++) {
            bf16x8 va[2];
#pragma unroll
            for (int kkb = 0; kkb < 2; kkb++)
                va[kkb] = ld_frag16(&Vc[db * 16 + ql][kkb * 32 + lg * 8]);
#pragma unroll
            for (int kkb = 0; kkb < 2; kkb++)
#pragma unroll
                for (int fn = 0; fn < 2; fn++)
                    oacc[db][fn] = __builtin_amdgcn_mfma_f32_16x16x32_bf16(va[kkb], pB[fn][kkb], oacc[db][fn], 0, 0, 0);
        }
        __builtin_amdgcn_s_setprio(0);

        if (hasn) {
#pragma unroll
            for (int j = 0; j < 2; j++) {
                *(uint4*)&Ks[cur ^ 1][srow][su + j * 8] = kn[j];
                *(uint4*)&Vs[cur ^ 1][srow][su + j * 8] = vn[j];
            }
            __syncthreads();
            cur ^= 1;
        }
    }

    // write unnormalized partials: A[kh][bh][q][d] f32, stats per q
#pragma unroll
    for (int fn = 0; fn < 2; fn++) {
        int q = qw + fn * 16 + ql;
        float* ap = pA + (((size_t)kh * 24 + bh) * NN + q) * DD + lg * 4;
#pragma unroll
        for (int db = 0; db < 4; db++)
            *(f32x4*)(ap + db * 16) = oacc[db][fn];
        if (lg == 0) {
            pm[((size_t)kh * 24 + bh) * NN + q] = mrun[fn];
            pl[((size_t)kh * 24 + bh) * NN + q] = lrun[fn];
        }
    }
}

// split-K combine: y = (A0*e0 + A1*e1) / (l0*e0 + l1*e1), written K-permuted bf16
__global__ void k_comb(const float* __restrict__ pA,
                       const float* __restrict__ pm,
                       const float* __restrict__ pl,
                       unsigned short* __restrict__ yws) {
    const int idx = blockIdx.x * blockDim.x + threadIdx.x;
    const int qg = idx >> 4;
    const int d4 = (idx & 15) * 4;
    const int bh = qg >> 11, q = qg & (NN - 1);
    const int b = bh / HH, h = bh % HH;
    const size_t half = (size_t)24 * NN * DD;
    float m0 = pm[qg], m1 = pm[24 * NN + qg];
    float l0 = pl[qg], l1 = pl[24 * NN + qg];
    float M = fmaxf(m0, m1);
    float e0 = exp2_hw(m0 - M), e1 = exp2_hw(m1 - M);
    float inv = 1.0f / (l0 * e0 + l1 * e1);
    f32x4 a0 = *(const f32x4*)(pA + (size_t)qg * DD + d4);
    f32x4 a1 = *(const f32x4*)(pA + half + (size_t)qg * DD + d4);
    ushort4 o;
    o.x = f2bf((a0[0] * e0 + a1[0] * e1) * inv);
    o.y = f2bf((a0[1] * e0 + a1[1] * e1) * inv);
    o.z = f2bf((a0[2] * e0 + a1[2] * e1) * inv);
    o.w = f2bf((a0[3] * e0 + a1[3] * e1) * inv);
    int dcol = (d4 & ~31) + ((d4 >> 2) & 3) * 8 + ((d4 >> 4) & 1) * 4;
    *(ushort4*)(yws + (size_t)(b * NN + q) * CC + h * DD + dcol) = o;
}

// ---------------- GEMM2: out = y @ W_out + b_out (f32 out) ----------------
__launch_bounds__(256)
__global__ void k_out(const unsigned short* __restrict__ yb,
                      const unsigned short* __restrict__ wt,
                      const float* __restrict__ bias,
                      float* __restrict__ out) {
    __shared__ unsigned short As[2][128 * 32];
    __shared__ unsigned short Bs[2][64 * 32];
    const int tid = threadIdx.x;
    const int lane = tid & 63, w = tid >> 6;
    const int ql = lane & 15, lg = lane >> 4;
    const int row0 = blockIdx.x * 128;
    const int j0 = blockIdx.y * 64;

    f32x4 acc[2][4];
#pragma unroll
    for (int a = 0; a < 2; a++)
#pragma unroll
        for (int b = 0; b < 4; b++) acc[a][b] = f32x4{0.f, 0.f, 0.f, 0.f};

    const int sr = lane >> 2;
    const int sc = (lane & 3) * 8;

    auto stage = [&](int bi, int k0) {
#pragma unroll
        for (int c = 0; c < 2; c++) {
            int j = w * 2 + c;
            gload16(yb + (size_t)(row0 + j * 16 + sr) * CC + k0 + sc, &As[bi][j * 512]);
        }
        gload16(wt + (size_t)(j0 + w * 16 + sr) * CC + k0 + sc, &Bs[bi][w * 512]);
    };

    stage(0, 0);
    __syncthreads();

    int bufi = 0;
    for (int k0 = 0; k0 < CC; k0 += 32) {
        if (k0 + 32 < CC) stage(bufi ^ 1, k0 + 32);
        bf16x8 af[2], bfr[4];
#pragma unroll
        for (int fr = 0; fr < 2; fr++)
            af[fr] = ld_frag16(&As[bufi][(w * 32 + fr * 16 + ql) * 32 + lg * 8]);
#pragma unroll
        for (int fn = 0; fn < 4; fn++)
            bfr[fn] = ld_frag16(&Bs[bufi][(fn * 16 + ql) * 32 + lg * 8]);
#pragma unroll
        for (int fr = 0; fr < 2; fr++)
#pragma unroll
            for (int fn = 0; fn < 4; fn++)
                acc[fr][fn] = __builtin_amdgcn_mfma_f32_16x16x32_bf16(af[fr], bfr[fn], acc[fr][fn], 0, 0, 0);
        __syncthreads();
        bufi ^= 1;
    }

#pragma unroll
    for (int fr = 0; fr < 2; fr++)
#pragma unroll
        for (int fn = 0; fn < 4; fn++) {
            float bj = bias[j0 + fn * 16 + ql];
#pragma unroll
            for (int r = 0; r < 4; r++) {
                int m = row0 + w * 32 + fr * 16 + lg * 4 + r;
                out[(size_t)m * CC + j0 + fn * 16 + ql] = acc[fr][fn][r] + bj;
            }
        }
}

extern "C" void kernel_launch(void* const* d_in, const int* in_sizes, int n_in,
                              void* d_out, int out_size, void* d_ws, size_t ws_size,
                              hipStream_t stream) {
    const float* x    = (const float*)d_in[0];
    const float* sinp = (const float*)d_in[1];
    const float* cosp = (const float*)d_in[2];
    const float* wqkv = (const float*)d_in[3];
    const float* bqkv = (const float*)d_in[4];
    const float* wout = (const float*)d_in[5];
    const float* bout = (const float*)d_in[6];
    float* out = (float*)d_out;
    char* ws = (char*)d_ws;

    unsigned short* xb  = (unsigned short*)(ws);            // 4096x768 bf16 (K-perm)
    unsigned short* wqb = (unsigned short*)(ws + 6291456);  // Wt_qkv [2304][768-perm]
    unsigned short* wob = (unsigned short*)(ws + 9830400);  // Wt_out [768][768-perm]
    unsigned short* qws = (unsigned short*)(ws + 11010048);
    unsigned short* kws = (unsigned short*)(ws + 17301504);
    unsigned short* vws = (unsigned short*)(ws + 23592960);
    unsigned short* yws = (unsigned short*)(ws + 29884416); // y [4096][768-perm]
    float* pA = (float*)(ws + 36175872);                    // 2 x 24 x 2048 x 64 f32
    float* pm = (float*)(ws + 61341696);                    // 2 x 24 x 2048 f32
    float* pl = (float*)(ws + 61734912);                    // 2 x 24 x 2048 f32
    if (ws_size < 62128128) return;  // split-K workspace verified present (R18)

    k_cvt<<<dim3(512), dim3(256), 0, stream>>>(x, xb, MM * CC / 4);
    k_cvtT<<<dim3(36, 12), dim3(256), 0, stream>>>(wqkv, wqb, CC, N3);
    k_cvtT<<<dim3(12, 12), dim3(256), 0, stream>>>(wout, wob, CC, CC);
    k_qkv<<<dim3(32, 36), dim3(256), 0, stream>>>(xb, wqb, bqkv, sinp, cosp, qws, kws, vws);
    k_attn4<<<dim3(768), dim3(256), 0, stream>>>(qws, kws, vws, pA, pm, pl);
    k_comb<<<dim3(3072), dim3(256), 0, stream>>>(pA, pm, pl, yws);
    k_out<<<dim3(32, 12), dim3(256), 0, stream>>>(yws, wob, bout, out);
}